// Round 1
// 447.313 us; speedup vs baseline: 1.1074x; 1.1074x over previous
//
#include <hip/hip_runtime.h>
#include <cstdint>
#include <cstddef>

// ---------------------------------------------------------------------------
// StokenAttention forward, MI355X. B=8, C=256, H=W=128, stoken 8x8 -> 16x16
// grid, n=256 stokens/batch, 64 px/stoken, NH=8 heads, HD=KD=32.
// R7: aff_agg rework.
//  (a) XCD-pair blockIdx swizzle: j-pairs sharing 64B x-granules co-locate on
//      one XCD (bid%8 round-robin) -> kills the 2x HBM over-fetch; whole
//      (b,i) rows per XCD -> stok_pad L2-local.
//  (b) phase 1: stage sf9 (2304 floats) into LDS once; wave = channel
//      quarter, lane = pixel; sf via uniform ds_read_b128 broadcast; cross-
//      wave combine via LDS float atomics (576-float buffer). VMEM instrs
//      per thread 592 -> ~25.
//  (c) pixs stride 65 -> 68: b128 staging stores + b128 phase-2 reads with
//      p-rotation (rot = (c>>3)&15) to avoid the stride-68 8-way conflict.
//      affs aliases dead sf9 LDS; total 81,296 B keeps 2 blocks/CU.
// ---------------------------------------------------------------------------

#define AFF_SCALE 0.0625f               // 256^-0.5
#define ATTN_SCALE 0.17677669529663687f // 32^-0.5

// ---------------------------------------------------------------------------
// K1: stoken avg-pool. grid = B*C*16, block = 128. Zero-padded [b][c][18][18].
// ---------------------------------------------------------------------------
__global__ __launch_bounds__(128) void stoken_kernel(
    const float* __restrict__ x, float* __restrict__ stok_pad)
{
    int blk = blockIdx.x;
    int i  = blk & 15;
    int bc = blk >> 4;                 // b*256 + c
    int t  = threadIdx.x;              // col 0..127
    const float* xr = x + ((size_t)bc * 128 + i * 8) * 128 + t;
    float s = 0.f;
#pragma unroll
    for (int r = 0; r < 8; ++r) s += xr[r * 128];
    s += __shfl_down(s, 4, 64);
    s += __shfl_down(s, 2, 64);
    s += __shfl_down(s, 1, 64);
    if ((t & 7) == 0) {
        int j = t >> 3;  // 0..15
        stok_pad[((size_t)bc * 18 + (i + 1)) * 18 + (j + 1)] = s * (1.f / 64.f);
    }
}

// ---------------------------------------------------------------------------
// K2: fused affinity + asum + aggregation. grid = B*256, block = 256.
// Output agg[b][n][k][c] with coalesced stores (NO atomics; fold done in K3).
// ---------------------------------------------------------------------------
__global__ __launch_bounds__(256) void aff_agg_kernel(
    const float* __restrict__ x, const float* __restrict__ stok_pad,
    float* __restrict__ aff_g, float* __restrict__ asum_g,
    float* __restrict__ agg)
{
    __shared__ __align__(16) float pixs[256 * 68]; // [c][p(64)+pad4], 69632 B
    __shared__ __align__(16) float sfs[9 * 260];   // ph1: sf9 [k][c]; later affs
    __shared__ __align__(16) float part[64 * 9];   // cross-wave logits [p][k]

    // XCD-pair swizzle (assumes bid -> XCD = bid & 7 round-robin):
    // pair = two blocks with j even/odd (share 64B x lines) on SAME xcd in
    // adjacent slots; consecutive pairs walk m then i then b, so each XCD
    // handles exactly one batch image and full (b,i) rows.
    int bid  = blockIdx.x;
    int xcd  = bid & 7, slot = bid >> 3;           // slot 0..255
    int pair = xcd * 128 + (slot >> 1);            // 0..1023 = (b,i,m)
    int m = pair & 7, i = (pair >> 3) & 15, b = pair >> 7;
    int j = m * 2 + (slot & 1);
    int bn = b * 256 + i * 16 + j;
    int t = threadIdx.x;

    // ---- stage pixel tile: 256 c x 64 p (b128 LDS stores) ----
    {
        int c0 = t >> 3, pi = t & 7;
#pragma unroll
        for (int it = 0; it < 8; ++it) {
            int c = c0 + 32 * it;
            const float* xp = x + (((size_t)b * 256 + c) * 128 + i * 8 + pi) * 128 + j * 8;
            float4 f0 = *(const float4*)&xp[0];
            float4 f1 = *(const float4*)&xp[4];
            *(float4*)&pixs[c * 68 + pi * 8]     = f0;
            *(float4*)&pixs[c * 68 + pi * 8 + 4] = f1;
        }
    }
    // ---- stage sf9: sfs[k*260+c] = stok_pad[b][c][i+dy][j+dx] (9/thread) ----
    {
        const float* sp = stok_pad + ((size_t)b * 256 + t) * 324 + i * 18 + j;
#pragma unroll
        for (int dy = 0; dy < 3; ++dy)
#pragma unroll
            for (int dx = 0; dx < 3; ++dx)
                sfs[(dy * 3 + dx) * 260 + t] = sp[dy * 18 + dx];
    }
    // zero the cross-wave logit accumulator (576 entries)
    part[t] = 0.f;
    part[t + 256] = 0.f;
    if (t < 64) part[t + 512] = 0.f;
    __syncthreads();

    // ---- phase 1: wave s = channels [64s,64s+64), lane = pixel.
    //      pix: 1 conflict-free b32/lane; sf: uniform b128 broadcast. ----
    {
        int s = t >> 6, p = t & 63;
        float acc[9] = {0.f,0.f,0.f,0.f,0.f,0.f,0.f,0.f,0.f};
        int cb = s * 64;
        for (int c4 = 0; c4 < 64; c4 += 4) {
            int c = cb + c4;
            float px0 = pixs[(c + 0) * 68 + p];
            float px1 = pixs[(c + 1) * 68 + p];
            float px2 = pixs[(c + 2) * 68 + p];
            float px3 = pixs[(c + 3) * 68 + p];
#pragma unroll
            for (int k = 0; k < 9; ++k) {
                const float4 sv = *(const float4*)&sfs[k * 260 + c];
                acc[k] += px0 * sv.x + px1 * sv.y + px2 * sv.z + px3 * sv.w;
            }
        }
#pragma unroll
        for (int k = 0; k < 9; ++k) atomicAdd(&part[p * 9 + k], acc[k]);
    }
    __syncthreads();

    float* affs = sfs;   // sf9 dead after phase 1; reuse as aff [k][64]

    // ---- phase 1.5: softmax over 9 (wave 0), aff + asum writes ----
    if (t < 64) {
        float a[9];
        float mx = -1e30f;
#pragma unroll
        for (int k = 0; k < 9; ++k) {
            float v = part[t * 9 + k] * AFF_SCALE;
            a[k] = v;
            mx = fmaxf(mx, v);
        }
        float ssum = 0.f;
#pragma unroll
        for (int k = 0; k < 9; ++k) { a[k] = __expf(a[k] - mx); ssum += a[k]; }
        float inv = 1.f / ssum;
#pragma unroll
        for (int k = 0; k < 9; ++k) {
            a[k] *= inv;
            affs[k * 64 + t] = a[k];
            aff_g[(size_t)bn * 576 + k * 64 + t] = a[k];
        }
#pragma unroll
        for (int k = 0; k < 9; ++k) {
            float r = a[k];
            r += __shfl_down(r, 32, 64); r += __shfl_down(r, 16, 64);
            r += __shfl_down(r, 8, 64);  r += __shfl_down(r, 4, 64);
            r += __shfl_down(r, 2, 64);  r += __shfl_down(r, 1, 64);
            if (t == 0) asum_g[(size_t)bn * 9 + k] = r;
        }
    }
    __syncthreads();

    // ---- phase 2: aggregation (thread = channel), b128 pixs + bcast affs.
    //      rot de-rotates the stride-68 bank pattern: lanes c and c+8 would
    //      otherwise hit the same bank-quad 8-way. ----
    {
        int c = t;
        int rot = (c >> 3) & 15;
        float a9[9] = {0.f,0.f,0.f,0.f,0.f,0.f,0.f,0.f,0.f};
        for (int p4i = 0; p4i < 16; ++p4i) {
            int p4 = (p4i + rot) & 15;
            const float4 pv = *(const float4*)&pixs[c * 68 + p4 * 4];
#pragma unroll
            for (int k = 0; k < 9; ++k) {
                const float4 av = *(const float4*)&affs[k * 64 + p4 * 4];
                a9[k] += pv.x * av.x + pv.y * av.y + pv.z * av.z + pv.w * av.w;
            }
        }
#pragma unroll
        for (int k = 0; k < 9; ++k)
            agg[((size_t)bn * 9 + k) * 256 + c] = a9[k];
    }
}

// ---------------------------------------------------------------------------
// K3: fold(agg)/(fold(asum)+1e-12) -> sf[b][c][n]. grid = B*16 (b,y), blk 256.
// ---------------------------------------------------------------------------
__global__ __launch_bounds__(256) void fold_div_kernel(
    const float* __restrict__ agg, const float* __restrict__ asum_g,
    float* __restrict__ sf)
{
    __shared__ float v[256 * 17];
    int b = blockIdx.x >> 4, y = blockIdx.x & 15;
    int t = threadIdx.x;  // c
    for (int x = 0; x < 16; ++x) {
        float af = 0.f, val = 0.f;
#pragma unroll
        for (int dy = 0; dy < 3; ++dy)
#pragma unroll
            for (int dx = 0; dx < 3; ++dx) {
                int ii = y + 1 - dy, jj = x + 1 - dx;
                if ((unsigned)ii < 16u && (unsigned)jj < 16u) {
                    int idx = (b * 256 + ii * 16 + jj) * 9 + dy * 3 + dx;
                    af  += asum_g[idx];                 // wave-uniform broadcast
                    val += agg[(size_t)idx * 256 + t];  // coalesced
                }
            }
        v[t * 17 + x] = val / (af + 1e-12f);
    }
    __syncthreads();
    int xw = t & 15, cw0 = t >> 4;
#pragma unroll
    for (int it = 0; it < 16; ++it) {
        int c = cw0 + it * 16;
        sf[((size_t)b * 256 + c) * 256 + y * 16 + xw] = v[c * 17 + xw];
    }
}

// ---------------------------------------------------------------------------
// K4/K7: GEMM out[b][o][n] = sum_c A[o][c] * Bm[b][c][n]. mode 0: [b][M][256].
// mode 1: write into padded [b][18][18][256] (+1 spatial offset).
// ---------------------------------------------------------------------------
__global__ __launch_bounds__(256) void gemm_w(
    const float* __restrict__ A, const float* __restrict__ Bm,
    float* __restrict__ Cout, int M, int mode)
{
    __shared__ float As[32 * 68];
    __shared__ float Bs[32 * 64];
    int b = blockIdx.x, o0 = blockIdx.y * 64, n0 = blockIdx.z * 64;
    int t = threadIdx.x;
    int tr = t >> 4, tc = t & 15;
    const float* Bb = Bm + (size_t)b * 256 * 256;
    float acc[4][4];
#pragma unroll
    for (int ii = 0; ii < 4; ++ii)
#pragma unroll
        for (int jj = 0; jj < 4; ++jj) acc[ii][jj] = 0.f;

    for (int k0 = 0; k0 < 256; k0 += 32) {
        {
            int ol = t >> 2, kq = (t & 3) * 8;
            const float* Ap = A + (size_t)(o0 + ol) * 256 + k0 + kq;
            const float4 f0 = *(const float4*)&Ap[0];
            const float4 f1 = *(const float4*)&Ap[4];
            As[(kq + 0) * 68 + ol] = f0.x; As[(kq + 1) * 68 + ol] = f0.y;
            As[(kq + 2) * 68 + ol] = f0.z; As[(kq + 3) * 68 + ol] = f0.w;
            As[(kq + 4) * 68 + ol] = f1.x; As[(kq + 5) * 68 + ol] = f1.y;
            As[(kq + 6) * 68 + ol] = f1.z; As[(kq + 7) * 68 + ol] = f1.w;
        }
#pragma unroll
        for (int i2 = 0; i2 < 8; ++i2) {
            int e = t + i2 * 256;
            int kl = e >> 6, nl = e & 63;
            Bs[kl * 64 + nl] = Bb[(size_t)(k0 + kl) * 256 + n0 + nl];
        }
        __syncthreads();
#pragma unroll
        for (int kk = 0; kk < 32; ++kk) {
            const float4 av = *(const float4*)&As[kk * 68 + tr * 4];
            const float4 bv = *(const float4*)&Bs[kk * 64 + tc * 4];
            acc[0][0] += av.x * bv.x; acc[0][1] += av.x * bv.y; acc[0][2] += av.x * bv.z; acc[0][3] += av.x * bv.w;
            acc[1][0] += av.y * bv.x; acc[1][1] += av.y * bv.y; acc[1][2] += av.y * bv.z; acc[1][3] += av.y * bv.w;
            acc[2][0] += av.z * bv.x; acc[2][1] += av.z * bv.y; acc[2][2] += av.z * bv.z; acc[2][3] += av.z * bv.w;
            acc[3][0] += av.w * bv.x; acc[3][1] += av.w * bv.y; acc[3][2] += av.w * bv.z; acc[3][3] += av.w * bv.w;
        }
        __syncthreads();
    }

    if (mode == 0) {
#pragma unroll
        for (int ii = 0; ii < 4; ++ii) {
            int o = o0 + tr * 4 + ii;
            float4 st = make_float4(acc[ii][0], acc[ii][1], acc[ii][2], acc[ii][3]);
            *(float4*)&Cout[((size_t)b * M + o) * 256 + n0 + tc * 4] = st;
        }
    } else {
#pragma unroll
        for (int jj = 0; jj < 4; ++jj) {
            int n = n0 + tc * 4 + jj;
            int y = n >> 4, x = n & 15;
            float4 st = make_float4(acc[0][jj], acc[1][jj], acc[2][jj], acc[3][jj]);
            *(float4*)&Cout[(((size_t)b * 18 + 1 + y) * 18 + 1 + x) * 256 + o0 + tr * 4] = st;
        }
    }
}

// ---------------------------------------------------------------------------
// K5: attention. grid = (8 b, 8 h, 4 n-tiles), block = 256.
// ---------------------------------------------------------------------------
__global__ __launch_bounds__(256) void attn_kernel(
    const float* __restrict__ qkv, float* __restrict__ o_attn)
{
    __shared__ float smem[9216];
    int b = blockIdx.x, h = blockIdx.y, nt = blockIdx.z;
    int t = threadIdx.x, nl = t & 63, mq = t >> 6;
    int n = nt * 64 + nl;

    {
        int dd = t >> 3, mb = (t & 7) * 32;
        const float* krow = qkv + ((size_t)b * 768 + h * 96 + 32 + dd) * 256;
#pragma unroll
        for (int e4 = 0; e4 < 8; ++e4) {
            int m = mb + e4 * 4;
            const float4 kw = *(const float4*)&krow[m];
            smem[(m + 0) * 32 + dd] = kw.x; smem[(m + 1) * 32 + dd] = kw.y;
            smem[(m + 2) * 32 + dd] = kw.z; smem[(m + 3) * 32 + dd] = kw.w;
        }
    }
    float q[32];
    {
        const float* qbase = qkv + ((size_t)b * 768 + h * 96) * 256 + n;
#pragma unroll
        for (int d = 0; d < 32; ++d) q[d] = qbase[(size_t)d * 256];
    }
    __syncthreads();

    float l[64];
#pragma unroll
    for (int e = 0; e < 64; ++e) {
        const float* kp = &smem[(mq * 64 + e) * 32];
        float s = 0.f;
#pragma unroll
        for (int d4 = 0; d4 < 8; ++d4) {
            const float4 kv4 = *(const float4*)&kp[d4 * 4];
            s += q[d4 * 4 + 0] * kv4.x + q[d4 * 4 + 1] * kv4.y +
                 q[d4 * 4 + 2] * kv4.z + q[d4 * 4 + 3] * kv4.w;
        }
        l[e] = s * ATTN_SCALE;
    }
    float mx = -1e30f;
#pragma unroll
    for (int e = 0; e < 64; ++e) mx = fmaxf(mx, l[e]);
    float sm = 0.f;
#pragma unroll
    for (int e = 0; e < 64; ++e) { l[e] = __expf(l[e] - mx); sm += l[e]; }
    __syncthreads();

    {
        int dd = t >> 3, mb = (t & 7) * 32;
        const float* vrow = qkv + ((size_t)b * 768 + h * 96 + 64 + dd) * 256;
#pragma unroll
        for (int e4 = 0; e4 < 8; ++e4) {
            int m = mb + e4 * 4;
            const float4 vw = *(const float4*)&vrow[m];
            smem[(m + 0) * 32 + dd] = vw.x; smem[(m + 1) * 32 + dd] = vw.y;
            smem[(m + 2) * 32 + dd] = vw.z; smem[(m + 3) * 32 + dd] = vw.w;
        }
    }
    __syncthreads();

    float oa[32];
#pragma unroll
    for (int d = 0; d < 32; ++d) oa[d] = 0.f;
#pragma unroll
    for (int e = 0; e < 64; ++e) {
        float pm = l[e];
        const float* vp = &smem[(mq * 64 + e) * 32];
#pragma unroll
        for (int d4 = 0; d4 < 8; ++d4) {
            const float4 vv = *(const float4*)&vp[d4 * 4];
            oa[d4 * 4 + 0] += pm * vv.x; oa[d4 * 4 + 1] += pm * vv.y;
            oa[d4 * 4 + 2] += pm * vv.z; oa[d4 * 4 + 3] += pm * vv.w;
        }
    }
    __syncthreads();

    float* op   = smem;          // [mq*64+nl][33]
    float* mxsm = smem + 8448;   // [idx][2]
    {
        int idx = mq * 64 + nl;
#pragma unroll
        for (int d = 0; d < 32; ++d) op[idx * 33 + d] = oa[d];
        mxsm[idx * 2 + 0] = mx;
        mxsm[idx * 2 + 1] = sm;
    }
    __syncthreads();

    if (t < 64) {
        float M2 = -1e30f;
#pragma unroll
        for (int q4 = 0; q4 < 4; ++q4) M2 = fmaxf(M2, mxsm[(q4 * 64 + t) * 2]);
        float w[4], S = 0.f;
#pragma unroll
        for (int q4 = 0; q4 < 4; ++q4) {
            w[q4] = __expf(mxsm[(q4 * 64 + t) * 2] - M2);
            S += mxsm[(q4 * 64 + t) * 2 + 1] * w[q4];
        }
        float inv = 1.f / S;
#pragma unroll
        for (int d = 0; d < 32; ++d) {
            float o = 0.f;
#pragma unroll
            for (int q4 = 0; q4 < 4; ++q4) o += op[(q4 * 64 + t) * 33 + d] * w[q4];
            o_attn[((size_t)b * 256 + h * 32 + d) * 256 + nt * 64 + t] = o * inv;
        }
    }
}

// ---------------------------------------------------------------------------
// K6: o += depthwise 3x3 PE conv of V. grid B*C, blk 256.
// ---------------------------------------------------------------------------
__global__ __launch_bounds__(256) void peadd_kernel(
    const float* __restrict__ qkv, const float* __restrict__ w_pe,
    float* __restrict__ o_attn)
{
    int bc = blockIdx.x;
    int b = bc >> 8, c = bc & 255;
    int t = threadIdx.x;
    int y = t >> 4, x = t & 15;
    int h = c >> 5, d = c & 31;
    const float* v = qkv + ((size_t)b * 768 + h * 96 + 64 + d) * 256;
    float acc = o_attn[(size_t)bc * 256 + t];
#pragma unroll
    for (int ky = 0; ky < 3; ++ky)
#pragma unroll
        for (int kx = 0; kx < 3; ++kx) {
            int yy = y + ky - 1, xx = x + kx - 1;
            if ((unsigned)yy < 16u && (unsigned)xx < 16u)
                acc += w_pe[c * 9 + ky * 3 + kx] * v[yy * 16 + xx];
        }
    o_attn[(size_t)bc * 256 + t] = acc;
}

// ---------------------------------------------------------------------------
// K8: scatter v3. grid = (b,i,pi) = 1024 blocks, block = 256.
// Block owns output row y = i*8+pi for ALL 256 c2 and all 128 x. Stores are
// 64-lane 256B contiguous (full 128B lines, no write-allocate).
// out[b,c2,y,x] = sum_k sfa_pad[b][i+dy][j+dx][(c2&3)*64+pi*8+pj]
//                       * aff[b, i*16+j][c2>>2][k],  j=x>>3, pj=x&7
// ---------------------------------------------------------------------------
__global__ __launch_bounds__(256) void scatter_kernel(
    const float* __restrict__ sfa_pad, const float* __restrict__ aff_g,
    float* __restrict__ out)
{
    __shared__ float ss[3 * 18 * 40];   // [dy][col][idx=q*8+d], stride 40
    __shared__ float aff_s[16 * 577];   // [j][p*9+k], stride 577 (>=576)

    int blk = blockIdx.x;
    int pi = blk & 7, i = (blk >> 3) & 15, b = blk >> 7;
    int t = threadIdx.x;

    // stage sfa neighborhood: 3 rows x 18 cols x 32 channels (this pi's slice)
    for (int e = t; e < 1728; e += 256) {
        int dy = e / 576, rem = e % 576;
        int col = rem >> 5, idx = rem & 31;
        int q = idx >> 3, d = idx & 7;
        ss[(dy * 18 + col) * 40 + idx] =
            sfa_pad[(((size_t)b * 18 + i + dy) * 18 + col) * 256 + q * 64 + pi * 8 + d];
    }
    // stage aff for the 16 stokens of row i: [j][p*9+k]
    {
        const float* ag = aff_g + ((size_t)b * 256 + i * 16) * 576;
        for (int e = t; e < 9216; e += 256) {
            int j = e / 576, rem = e % 576;
            int k = rem >> 6, p = rem & 63;
            aff_s[j * 577 + p * 9 + k] = ag[j * 576 + rem];
        }
    }
    __syncthreads();

    int lane = t & 63, w = t >> 6;
    int j0 = lane >> 3, pj = lane & 7;
    int j1 = j0 + 8;

    // register-cache the 2x36 sfa values this lane needs
    float S0[4][9], S1[4][9];
#pragma unroll
    for (int q = 0; q < 4; ++q)
#pragma unroll
        for (int k = 0; k < 9; ++k) {
            int dy = k / 3, dx = k % 3;
            S0[q][k] = ss[(dy * 18 + j0 + dx) * 40 + q * 8 + pj];
            S1[q][k] = ss[(dy * 18 + j1 + dx) * 40 + q * 8 + pj];
        }

    int y = i * 8 + pi;
    size_t ob = (size_t)b * 256 * 16384 + (size_t)y * 128;
    const float* A0 = &aff_s[j0 * 577];
    const float* A1 = &aff_s[j1 * 577];
    for (int p = w * 16; p < w * 16 + 16; ++p) {
        float a0[9], a1[9];
#pragma unroll
        for (int k = 0; k < 9; ++k) { a0[k] = A0[p * 9 + k]; a1[k] = A1[p * 9 + k]; }
#pragma unroll
        for (int q = 0; q < 4; ++q) {
            int c2 = p * 4 + q;
            float v0 = 0.f, v1 = 0.f;
#pragma unroll
            for (int k = 0; k < 9; ++k) {
                v0 += S0[q][k] * a0[k];
                v1 += S1[q][k] * a1[k];
            }
            out[ob + (size_t)c2 * 16384 + lane] = v0;
            out[ob + (size_t)c2 * 16384 + 64 + lane] = v1;
        }
    }
}

// ---------------------------------------------------------------------------
// launch. Workspace (floats), 15.8 MB; agg (18.9 MB) lives in d_out scratch
// (dead before scatter writes out).
// ---------------------------------------------------------------------------
extern "C" void kernel_launch(void* const* d_in, const int* in_sizes, int n_in,
                              void* d_out, int out_size, void* d_ws, size_t ws_size,
                              hipStream_t stream) {
    const float* x      = (const float*)d_in[0];
    const float* w_qkv  = (const float*)d_in[1];
    const float* w_pe   = (const float*)d_in[2];
    const float* w_proj = (const float*)d_in[3];
    float* out = (float*)d_out;
    float* agg = (float*)d_out;  // scratch: 18.9 MB << 134 MB, dead before scatter

    float* ws = (float*)d_ws;
    const size_t o_aff  = 0;
    const size_t o_asum = 1179648;
    const size_t o_pad  = 1198080;
    const size_t o_sf   = 1861632;
    const size_t o_qkv  = 2385920;

    hipMemsetAsync(ws + o_pad, 0, 663552 * sizeof(float), stream);

    stoken_kernel<<<8 * 256 * 16, 128, 0, stream>>>(x, ws + o_pad);
    aff_agg_kernel<<<8 * 256, 256, 0, stream>>>(x, ws + o_pad, ws + o_aff,
                                                ws + o_asum, agg);
    fold_div_kernel<<<8 * 16, 256, 0, stream>>>(agg, ws + o_asum, ws + o_sf);
    gemm_w<<<dim3(8, 12, 4), 256, 0, stream>>>(w_qkv, ws + o_sf, ws + o_qkv, 768, 0);
    // stok_pad dead; re-zero region for sfa_pad (borders must be 0)
    hipMemsetAsync(ws + o_pad, 0, 663552 * sizeof(float), stream);
    attn_kernel<<<dim3(8, 8, 4), 256, 0, stream>>>(ws + o_qkv, ws + o_sf);
    peadd_kernel<<<8 * 256, 256, 0, stream>>>(ws + o_qkv, w_pe, ws + o_sf);
    gemm_w<<<dim3(8, 4, 4), 256, 0, stream>>>(w_proj, ws + o_sf, ws + o_pad, 256, 1);
    scatter_kernel<<<8 * 16 * 8, 256, 0, stream>>>(ws + o_pad, ws + o_aff, out);
}

// Round 3
// 442.862 us; speedup vs baseline: 1.1186x; 1.0101x over previous
//
#include <hip/hip_runtime.h>
#include <cstdint>
#include <cstddef>

// ---------------------------------------------------------------------------
// StokenAttention forward, MI355X. B=8, C=256, H=W=128, stoken 8x8 -> 16x16
// grid, n=256 stokens/batch, 64 px/stoken, NH=8 heads, HD=KD=32.
// R9: R8 with the part[] zeroing bug fixed (R8's `if (t<320) part[t+256]=0`
// left part[512..575] uninitialized -> stale-LDS corruption of pixels 57..63;
// correct form zeroes all 576 entries). R8 design unchanged:
// phase 1 lane = (p-quad x 16c), phase 2 lane = (c-quad x 16p): each b128
// operand feeds 16 MACs -> ds-reads/thread 368 -> 104. Cross-lane reduce via
// shfl_xor(1,2) + select; lane l ends up owning p=l (ph1) / c=w*64+l (ph2).
// Quad-slot swizzle slot = p4 ^ ((c>>2)&3) keeps staging + both read phases
// conflict-free. stok_pad channel-last [b][18][18][256] -> coalesced sf9.
// ---------------------------------------------------------------------------

#define AFF_SCALE 0.0625f               // 256^-0.5
#define ATTN_SCALE 0.17677669529663687f // 32^-0.5

// ---------------------------------------------------------------------------
// K1: stoken avg-pool. grid = B*C*16, block = 128. Zero-padded channel-last
// output [b][18][18][256].
// ---------------------------------------------------------------------------
__global__ __launch_bounds__(128) void stoken_kernel(
    const float* __restrict__ x, float* __restrict__ stok_pad)
{
    int blk = blockIdx.x;
    int i  = blk & 15;
    int bc = blk >> 4;                 // b*256 + c
    int t  = threadIdx.x;              // col 0..127
    const float* xr = x + ((size_t)bc * 128 + i * 8) * 128 + t;
    float s = 0.f;
#pragma unroll
    for (int r = 0; r < 8; ++r) s += xr[r * 128];
    s += __shfl_down(s, 4, 64);
    s += __shfl_down(s, 2, 64);
    s += __shfl_down(s, 1, 64);
    if ((t & 7) == 0) {
        int j = t >> 3;  // 0..15
        int b = bc >> 8, c = bc & 255;
        stok_pad[(((size_t)b * 18 + (i + 1)) * 18 + (j + 1)) * 256 + c] =
            s * (1.f / 64.f);
    }
}

// ---------------------------------------------------------------------------
// K2: fused affinity + asum + aggregation. grid = B*256, block = 256.
// Output agg[b][n][k][c] with coalesced stores (NO atomics; fold done in K3).
// ---------------------------------------------------------------------------
__global__ __launch_bounds__(256) void aff_agg_kernel(
    const float* __restrict__ x, const float* __restrict__ stok_pad,
    float* __restrict__ aff_g, float* __restrict__ asum_g,
    float* __restrict__ agg)
{
    __shared__ __align__(16) float pixs[256 * 68]; // [c][16 quad-slots], 69632 B
    __shared__ __align__(16) float sfs[9 * 260];   // ph1: sf9 [k][c]; later affs
    __shared__ __align__(16) float part[576];      // logits [p][k]

    // XCD-pair swizzle (bid -> XCD = bid & 7 round-robin): j even/odd pairs
    // (share 64B x lines) on same XCD; each XCD owns one batch image.
    int bid  = blockIdx.x;
    int xcd  = bid & 7, slot_ = bid >> 3;          // slot 0..255
    int pair = xcd * 128 + (slot_ >> 1);           // 0..1023 = (b,i,m)
    int m = pair & 7, i = (pair >> 3) & 15, b = pair >> 7;
    int j = m * 2 + (slot_ & 1);
    int bn = b * 256 + i * 16 + j;
    int t = threadIdx.x;

    // ---- stage pixel tile: 256 c x 64 p, quad-swizzled slots ----
    {
        int c0 = t >> 3, pi = t & 7;
#pragma unroll
        for (int it = 0; it < 8; ++it) {
            int c = c0 + 32 * it;
            const float* xp = x + (((size_t)b * 256 + c) * 128 + i * 8 + pi) * 128 + j * 8;
            float4 f0 = *(const float4*)&xp[0];
            float4 f1 = *(const float4*)&xp[4];
            int gma = (c >> 2) & 3;
            int s0 = (2 * pi) ^ gma, s1 = (2 * pi + 1) ^ gma;
            *(float4*)&pixs[c * 68 + s0 * 4] = f0;
            *(float4*)&pixs[c * 68 + s1 * 4] = f1;
        }
    }
    // ---- stage sf9 (channel-last stok_pad -> coalesced): sfs[k][c] ----
    {
        const float* spT = stok_pad + (size_t)b * 324 * 256;
#pragma unroll
        for (int dy = 0; dy < 3; ++dy)
#pragma unroll
            for (int dx = 0; dx < 3; ++dx)
                sfs[(dy * 3 + dx) * 260 + t] =
                    spT[((size_t)(i + dy) * 18 + (j + dx)) * 256 + t];
    }
    // zero logit accumulator (ALL 576 entries — R8 bug was here)
    part[t] = 0.f;
    part[t + 256] = 0.f;
    if (t < 64) part[t + 512] = 0.f;
    __syncthreads();

    int w = t >> 6, l = t & 63;

    // ---- phase 1: lane = (p-quad pq, c-sixteenth cgl); acc[4p][9k].
    //      Each b128 (pix quad / sf quad) feeds 16 MACs. ----
    {
        int pq = l >> 2, cgl = l & 3;
        int cbase = w * 64 + cgl * 16;
        float acc[4][9];
#pragma unroll
        for (int ii = 0; ii < 4; ++ii)
#pragma unroll
            for (int k = 0; k < 9; ++k) acc[ii][k] = 0.f;

#pragma unroll
        for (int c4i = 0; c4i < 4; ++c4i) {
            int c = cbase + c4i * 4;
            int slot = (pq ^ c4i) * 4;     // gamma(c)=c4i for this c-range
            const float4 p0 = *(const float4*)&pixs[(c + 0) * 68 + slot];
            const float4 p1 = *(const float4*)&pixs[(c + 1) * 68 + slot];
            const float4 p2 = *(const float4*)&pixs[(c + 2) * 68 + slot];
            const float4 p3 = *(const float4*)&pixs[(c + 3) * 68 + slot];
#pragma unroll
            for (int k = 0; k < 9; ++k) {
                const float4 sv = *(const float4*)&sfs[k * 260 + c];
                acc[0][k] += p0.x * sv.x + p1.x * sv.y + p2.x * sv.z + p3.x * sv.w;
                acc[1][k] += p0.y * sv.x + p1.y * sv.y + p2.y * sv.z + p3.y * sv.w;
                acc[2][k] += p0.z * sv.x + p1.z * sv.y + p2.z * sv.z + p3.z * sv.w;
                acc[3][k] += p0.w * sv.x + p1.w * sv.y + p2.w * sv.z + p3.w * sv.w;
            }
        }
        // reduce over cgl (lanes l^1, l^2); then lane l owns p = l
#pragma unroll
        for (int ii = 0; ii < 4; ++ii)
#pragma unroll
            for (int k = 0; k < 9; ++k) {
                acc[ii][k] += __shfl_xor(acc[ii][k], 1, 64);
                acc[ii][k] += __shfl_xor(acc[ii][k], 2, 64);
            }
#pragma unroll
        for (int k = 0; k < 9; ++k) {
            float v01 = (cgl & 1) ? acc[1][k] : acc[0][k];
            float v23 = (cgl & 1) ? acc[3][k] : acc[2][k];
            float vk  = (cgl & 2) ? v23 : v01;
            atomicAdd(&part[l * 9 + k], vk);
        }
    }
    __syncthreads();

    float* affs = sfs;   // sf9 dead; reuse as aff [k][64]

    // ---- phase 1.5: softmax over 9 (wave 0), aff + asum writes ----
    if (t < 64) {
        float a[9];
        float mx = -1e30f;
#pragma unroll
        for (int k = 0; k < 9; ++k) {
            float v = part[t * 9 + k] * AFF_SCALE;
            a[k] = v;
            mx = fmaxf(mx, v);
        }
        float ssum = 0.f;
#pragma unroll
        for (int k = 0; k < 9; ++k) { a[k] = __expf(a[k] - mx); ssum += a[k]; }
        float inv = 1.f / ssum;
#pragma unroll
        for (int k = 0; k < 9; ++k) {
            a[k] *= inv;
            affs[k * 64 + t] = a[k];
            aff_g[(size_t)bn * 576 + k * 64 + t] = a[k];
        }
#pragma unroll
        for (int k = 0; k < 9; ++k) {
            float r = a[k];
            r += __shfl_down(r, 32, 64); r += __shfl_down(r, 16, 64);
            r += __shfl_down(r, 8, 64);  r += __shfl_down(r, 4, 64);
            r += __shfl_down(r, 2, 64);  r += __shfl_down(r, 1, 64);
            if (t == 0) asum_g[(size_t)bn * 9 + k] = r;
        }
    }
    __syncthreads();

    // ---- phase 2: lane = (c-quad cql, p-sixteenth pq2); acc2[4c][9k].
    //      After reduce over pq2, lane l owns c = w*64 + l -> coalesced. ----
    {
        int cql = l >> 2, pq2 = l & 3;
        int cb2 = w * 64 + cql * 4;
        int gma = cql & 3;                 // gamma(c) for c in cb2..cb2+3
        float acc2[4][9];
#pragma unroll
        for (int ii = 0; ii < 4; ++ii)
#pragma unroll
            for (int k = 0; k < 9; ++k) acc2[ii][k] = 0.f;

#pragma unroll
        for (int pp = 0; pp < 4; ++pp) {
            int p4 = pq2 * 4 + pp;         // p-quad index 0..15
            int slot = (p4 ^ gma) * 4;
            const float4 q0 = *(const float4*)&pixs[(cb2 + 0) * 68 + slot];
            const float4 q1 = *(const float4*)&pixs[(cb2 + 1) * 68 + slot];
            const float4 q2 = *(const float4*)&pixs[(cb2 + 2) * 68 + slot];
            const float4 q3 = *(const float4*)&pixs[(cb2 + 3) * 68 + slot];
#pragma unroll
            for (int k = 0; k < 9; ++k) {
                const float4 av = *(const float4*)&affs[k * 64 + p4 * 4];
                acc2[0][k] += q0.x * av.x + q0.y * av.y + q0.z * av.z + q0.w * av.w;
                acc2[1][k] += q1.x * av.x + q1.y * av.y + q1.z * av.z + q1.w * av.w;
                acc2[2][k] += q2.x * av.x + q2.y * av.y + q2.z * av.z + q2.w * av.w;
                acc2[3][k] += q3.x * av.x + q3.y * av.y + q3.z * av.z + q3.w * av.w;
            }
        }
        // reduce over pq2 (lanes l^1, l^2); then lane l owns c = w*64 + l
#pragma unroll
        for (int ii = 0; ii < 4; ++ii)
#pragma unroll
            for (int k = 0; k < 9; ++k) {
                acc2[ii][k] += __shfl_xor(acc2[ii][k], 1, 64);
                acc2[ii][k] += __shfl_xor(acc2[ii][k], 2, 64);
            }
        int cout = w * 64 + l;
#pragma unroll
        for (int k = 0; k < 9; ++k) {
            float v01 = (pq2 & 1) ? acc2[1][k] : acc2[0][k];
            float v23 = (pq2 & 1) ? acc2[3][k] : acc2[2][k];
            float vk  = (pq2 & 2) ? v23 : v01;
            agg[((size_t)bn * 9 + k) * 256 + cout] = vk;
        }
    }
}

// ---------------------------------------------------------------------------
// K3: fold(agg)/(fold(asum)+1e-12) -> sf[b][c][n]. grid = B*16 (b,y), blk 256.
// ---------------------------------------------------------------------------
__global__ __launch_bounds__(256) void fold_div_kernel(
    const float* __restrict__ agg, const float* __restrict__ asum_g,
    float* __restrict__ sf)
{
    __shared__ float v[256 * 17];
    int b = blockIdx.x >> 4, y = blockIdx.x & 15;
    int t = threadIdx.x;  // c
    for (int x = 0; x < 16; ++x) {
        float af = 0.f, val = 0.f;
#pragma unroll
        for (int dy = 0; dy < 3; ++dy)
#pragma unroll
            for (int dx = 0; dx < 3; ++dx) {
                int ii = y + 1 - dy, jj = x + 1 - dx;
                if ((unsigned)ii < 16u && (unsigned)jj < 16u) {
                    int idx = (b * 256 + ii * 16 + jj) * 9 + dy * 3 + dx;
                    af  += asum_g[idx];                 // wave-uniform broadcast
                    val += agg[(size_t)idx * 256 + t];  // coalesced
                }
            }
        v[t * 17 + x] = val / (af + 1e-12f);
    }
    __syncthreads();
    int xw = t & 15, cw0 = t >> 4;
#pragma unroll
    for (int it = 0; it < 16; ++it) {
        int c = cw0 + it * 16;
        sf[((size_t)b * 256 + c) * 256 + y * 16 + xw] = v[c * 17 + xw];
    }
}

// ---------------------------------------------------------------------------
// K4/K7: GEMM out[b][o][n] = sum_c A[o][c] * Bm[b][c][n]. mode 0: [b][M][256].
// mode 1: write into padded [b][18][18][256] (+1 spatial offset).
// ---------------------------------------------------------------------------
__global__ __launch_bounds__(256) void gemm_w(
    const float* __restrict__ A, const float* __restrict__ Bm,
    float* __restrict__ Cout, int M, int mode)
{
    __shared__ float As[32 * 68];
    __shared__ float Bs[32 * 64];
    int b = blockIdx.x, o0 = blockIdx.y * 64, n0 = blockIdx.z * 64;
    int t = threadIdx.x;
    int tr = t >> 4, tc = t & 15;
    const float* Bb = Bm + (size_t)b * 256 * 256;
    float acc[4][4];
#pragma unroll
    for (int ii = 0; ii < 4; ++ii)
#pragma unroll
        for (int jj = 0; jj < 4; ++jj) acc[ii][jj] = 0.f;

    for (int k0 = 0; k0 < 256; k0 += 32) {
        {
            int ol = t >> 2, kq = (t & 3) * 8;
            const float* Ap = A + (size_t)(o0 + ol) * 256 + k0 + kq;
            const float4 f0 = *(const float4*)&Ap[0];
            const float4 f1 = *(const float4*)&Ap[4];
            As[(kq + 0) * 68 + ol] = f0.x; As[(kq + 1) * 68 + ol] = f0.y;
            As[(kq + 2) * 68 + ol] = f0.z; As[(kq + 3) * 68 + ol] = f0.w;
            As[(kq + 4) * 68 + ol] = f1.x; As[(kq + 5) * 68 + ol] = f1.y;
            As[(kq + 6) * 68 + ol] = f1.z; As[(kq + 7) * 68 + ol] = f1.w;
        }
#pragma unroll
        for (int i2 = 0; i2 < 8; ++i2) {
            int e = t + i2 * 256;
            int kl = e >> 6, nl = e & 63;
            Bs[kl * 64 + nl] = Bb[(size_t)(k0 + kl) * 256 + n0 + nl];
        }
        __syncthreads();
#pragma unroll
        for (int kk = 0; kk < 32; ++kk) {
            const float4 av = *(const float4*)&As[kk * 68 + tr * 4];
            const float4 bv = *(const float4*)&Bs[kk * 64 + tc * 4];
            acc[0][0] += av.x * bv.x; acc[0][1] += av.x * bv.y; acc[0][2] += av.x * bv.z; acc[0][3] += av.x * bv.w;
            acc[1][0] += av.y * bv.x; acc[1][1] += av.y * bv.y; acc[1][2] += av.y * bv.z; acc[1][3] += av.y * bv.w;
            acc[2][0] += av.z * bv.x; acc[2][1] += av.z * bv.y; acc[2][2] += av.z * bv.z; acc[2][3] += av.z * bv.w;
            acc[3][0] += av.w * bv.x; acc[3][1] += av.w * bv.y; acc[3][2] += av.w * bv.z; acc[3][3] += av.w * bv.w;
        }
        __syncthreads();
    }

    if (mode == 0) {
#pragma unroll
        for (int ii = 0; ii < 4; ++ii) {
            int o = o0 + tr * 4 + ii;
            float4 st = make_float4(acc[ii][0], acc[ii][1], acc[ii][2], acc[ii][3]);
            *(float4*)&Cout[((size_t)b * M + o) * 256 + n0 + tc * 4] = st;
        }
    } else {
#pragma unroll
        for (int jj = 0; jj < 4; ++jj) {
            int n = n0 + tc * 4 + jj;
            int y = n >> 4, x = n & 15;
            float4 st = make_float4(acc[0][jj], acc[1][jj], acc[2][jj], acc[3][jj]);
            *(float4*)&Cout[(((size_t)b * 18 + 1 + y) * 18 + 1 + x) * 256 + o0 + tr * 4] = st;
        }
    }
}

// ---------------------------------------------------------------------------
// K5: attention. grid = (8 b, 8 h, 4 n-tiles), block = 256.
// ---------------------------------------------------------------------------
__global__ __launch_bounds__(256) void attn_kernel(
    const float* __restrict__ qkv, float* __restrict__ o_attn)
{
    __shared__ float smem[9216];
    int b = blockIdx.x, h = blockIdx.y, nt = blockIdx.z;
    int t = threadIdx.x, nl = t & 63, mq = t >> 6;
    int n = nt * 64 + nl;

    {
        int dd = t >> 3, mb = (t & 7) * 32;
        const float* krow = qkv + ((size_t)b * 768 + h * 96 + 32 + dd) * 256;
#pragma unroll
        for (int e4 = 0; e4 < 8; ++e4) {
            int m = mb + e4 * 4;
            const float4 kw = *(const float4*)&krow[m];
            smem[(m + 0) * 32 + dd] = kw.x; smem[(m + 1) * 32 + dd] = kw.y;
            smem[(m + 2) * 32 + dd] = kw.z; smem[(m + 3) * 32 + dd] = kw.w;
        }
    }
    float q[32];
    {
        const float* qbase = qkv + ((size_t)b * 768 + h * 96) * 256 + n;
#pragma unroll
        for (int d = 0; d < 32; ++d) q[d] = qbase[(size_t)d * 256];
    }
    __syncthreads();

    float l[64];
#pragma unroll
    for (int e = 0; e < 64; ++e) {
        const float* kp = &smem[(mq * 64 + e) * 32];
        float s = 0.f;
#pragma unroll
        for (int d4 = 0; d4 < 8; ++d4) {
            const float4 kv4 = *(const float4*)&kp[d4 * 4];
            s += q[d4 * 4 + 0] * kv4.x + q[d4 * 4 + 1] * kv4.y +
                 q[d4 * 4 + 2] * kv4.z + q[d4 * 4 + 3] * kv4.w;
        }
        l[e] = s * ATTN_SCALE;
    }
    float mx = -1e30f;
#pragma unroll
    for (int e = 0; e < 64; ++e) mx = fmaxf(mx, l[e]);
    float sm = 0.f;
#pragma unroll
    for (int e = 0; e < 64; ++e) { l[e] = __expf(l[e] - mx); sm += l[e]; }
    __syncthreads();

    {
        int dd = t >> 3, mb = (t & 7) * 32;
        const float* vrow = qkv + ((size_t)b * 768 + h * 96 + 64 + dd) * 256;
#pragma unroll
        for (int e4 = 0; e4 < 8; ++e4) {
            int m = mb + e4 * 4;
            const float4 vw = *(const float4*)&vrow[m];
            smem[(m + 0) * 32 + dd] = vw.x; smem[(m + 1) * 32 + dd] = vw.y;
            smem[(m + 2) * 32 + dd] = vw.z; smem[(m + 3) * 32 + dd] = vw.w;
        }
    }
    __syncthreads();

    float oa[32];
#pragma unroll
    for (int d = 0; d < 32; ++d) oa[d] = 0.f;
#pragma unroll
    for (int e = 0; e < 64; ++e) {
        float pm = l[e];
        const float* vp = &smem[(mq * 64 + e) * 32];
#pragma unroll
        for (int d4 = 0; d4 < 8; ++d4) {
            const float4 vv = *(const float4*)&vp[d4 * 4];
            oa[d4 * 4 + 0] += pm * vv.x; oa[d4 * 4 + 1] += pm * vv.y;
            oa[d4 * 4 + 2] += pm * vv.z; oa[d4 * 4 + 3] += pm * vv.w;
        }
    }
    __syncthreads();

    float* op   = smem;          // [mq*64+nl][33]
    float* mxsm = smem + 8448;   // [idx][2]
    {
        int idx = mq * 64 + nl;
#pragma unroll
        for (int d = 0; d < 32; ++d) op[idx * 33 + d] = oa[d];
        mxsm[idx * 2 + 0] = mx;
        mxsm[idx * 2 + 1] = sm;
    }
    __syncthreads();

    if (t < 64) {
        float M2 = -1e30f;
#pragma unroll
        for (int q4 = 0; q4 < 4; ++q4) M2 = fmaxf(M2, mxsm[(q4 * 64 + t) * 2]);
        float w[4], S = 0.f;
#pragma unroll
        for (int q4 = 0; q4 < 4; ++q4) {
            w[q4] = __expf(mxsm[(q4 * 64 + t) * 2] - M2);
            S += mxsm[(q4 * 64 + t) * 2 + 1] * w[q4];
        }
        float inv = 1.f / S;
#pragma unroll
        for (int d = 0; d < 32; ++d) {
            float o = 0.f;
#pragma unroll
            for (int q4 = 0; q4 < 4; ++q4) o += op[(q4 * 64 + t) * 33 + d] * w[q4];
            o_attn[((size_t)b * 256 + h * 32 + d) * 256 + nt * 64 + t] = o * inv;
        }
    }
}

// ---------------------------------------------------------------------------
// K6: o += depthwise 3x3 PE conv of V. grid B*C, blk 256.
// ---------------------------------------------------------------------------
__global__ __launch_bounds__(256) void peadd_kernel(
    const float* __restrict__ qkv, const float* __restrict__ w_pe,
    float* __restrict__ o_attn)
{
    int bc = blockIdx.x;
    int b = bc >> 8, c = bc & 255;
    int t = threadIdx.x;
    int y = t >> 4, x = t & 15;
    int h = c >> 5, d = c & 31;
    const float* v = qkv + ((size_t)b * 768 + h * 96 + 64 + d) * 256;
    float acc = o_attn[(size_t)bc * 256 + t];
#pragma unroll
    for (int ky = 0; ky < 3; ++ky)
#pragma unroll
        for (int kx = 0; kx < 3; ++kx) {
            int yy = y + ky - 1, xx = x + kx - 1;
            if ((unsigned)yy < 16u && (unsigned)xx < 16u)
                acc += w_pe[c * 9 + ky * 3 + kx] * v[yy * 16 + xx];
        }
    o_attn[(size_t)bc * 256 + t] = acc;
}

// ---------------------------------------------------------------------------
// K8: scatter v3. grid = (b,i,pi) = 1024 blocks, block = 256.
// Block owns output row y = i*8+pi for ALL 256 c2 and all 128 x. Stores are
// 64-lane 256B contiguous (full 128B lines, no write-allocate).
// out[b,c2,y,x] = sum_k sfa_pad[b][i+dy][j+dx][(c2&3)*64+pi*8+pj]
//                       * aff[b, i*16+j][c2>>2][k],  j=x>>3, pj=x&7
// ---------------------------------------------------------------------------
__global__ __launch_bounds__(256) void scatter_kernel(
    const float* __restrict__ sfa_pad, const float* __restrict__ aff_g,
    float* __restrict__ out)
{
    __shared__ float ss[3 * 18 * 40];   // [dy][col][idx=q*8+d], stride 40
    __shared__ float aff_s[16 * 577];   // [j][p*9+k], stride 577 (>=576)

    int blk = blockIdx.x;
    int pi = blk & 7, i = (blk >> 3) & 15, b = blk >> 7;
    int t = threadIdx.x;

    // stage sfa neighborhood: 3 rows x 18 cols x 32 channels (this pi's slice)
    for (int e = t; e < 1728; e += 256) {
        int dy = e / 576, rem = e % 576;
        int col = rem >> 5, idx = rem & 31;
        int q = idx >> 3, d = idx & 7;
        ss[(dy * 18 + col) * 40 + idx] =
            sfa_pad[(((size_t)b * 18 + i + dy) * 18 + col) * 256 + q * 64 + pi * 8 + d];
    }
    // stage aff for the 16 stokens of row i: [j][p*9+k]
    {
        const float* ag = aff_g + ((size_t)b * 256 + i * 16) * 576;
        for (int e = t; e < 9216; e += 256) {
            int j = e / 576, rem = e % 576;
            int k = rem >> 6, p = rem & 63;
            aff_s[j * 577 + p * 9 + k] = ag[j * 576 + rem];
        }
    }
    __syncthreads();

    int lane = t & 63, w = t >> 6;
    int j0 = lane >> 3, pj = lane & 7;
    int j1 = j0 + 8;

    // register-cache the 2x36 sfa values this lane needs
    float S0[4][9], S1[4][9];
#pragma unroll
    for (int q = 0; q < 4; ++q)
#pragma unroll
        for (int k = 0; k < 9; ++k) {
            int dy = k / 3, dx = k % 3;
            S0[q][k] = ss[(dy * 18 + j0 + dx) * 40 + q * 8 + pj];
            S1[q][k] = ss[(dy * 18 + j1 + dx) * 40 + q * 8 + pj];
        }

    int y = i * 8 + pi;
    size_t ob = (size_t)b * 256 * 16384 + (size_t)y * 128;
    const float* A0 = &aff_s[j0 * 577];
    const float* A1 = &aff_s[j1 * 577];
    for (int p = w * 16; p < w * 16 + 16; ++p) {
        float a0[9], a1[9];
#pragma unroll
        for (int k = 0; k < 9; ++k) { a0[k] = A0[p * 9 + k]; a1[k] = A1[p * 9 + k]; }
#pragma unroll
        for (int q = 0; q < 4; ++q) {
            int c2 = p * 4 + q;
            float v0 = 0.f, v1 = 0.f;
#pragma unroll
            for (int k = 0; k < 9; ++k) {
                v0 += S0[q][k] * a0[k];
                v1 += S1[q][k] * a1[k];
            }
            out[ob + (size_t)c2 * 16384 + lane] = v0;
            out[ob + (size_t)c2 * 16384 + 64 + lane] = v1;
        }
    }
}

// ---------------------------------------------------------------------------
// launch. Workspace (floats), 15.8 MB; agg (18.9 MB) lives in d_out scratch
// (dead before scatter writes out).
// ---------------------------------------------------------------------------
extern "C" void kernel_launch(void* const* d_in, const int* in_sizes, int n_in,
                              void* d_out, int out_size, void* d_ws, size_t ws_size,
                              hipStream_t stream) {
    const float* x      = (const float*)d_in[0];
    const float* w_qkv  = (const float*)d_in[1];
    const float* w_pe   = (const float*)d_in[2];
    const float* w_proj = (const float*)d_in[3];
    float* out = (float*)d_out;
    float* agg = (float*)d_out;  // scratch: 18.9 MB << 134 MB, dead before scatter

    float* ws = (float*)d_ws;
    const size_t o_aff  = 0;
    const size_t o_asum = 1179648;
    const size_t o_pad  = 1198080;
    const size_t o_sf   = 1861632;
    const size_t o_qkv  = 2385920;

    hipMemsetAsync(ws + o_pad, 0, 663552 * sizeof(float), stream);

    stoken_kernel<<<8 * 256 * 16, 128, 0, stream>>>(x, ws + o_pad);
    aff_agg_kernel<<<8 * 256, 256, 0, stream>>>(x, ws + o_pad, ws + o_aff,
                                                ws + o_asum, agg);
    fold_div_kernel<<<8 * 16, 256, 0, stream>>>(agg, ws + o_asum, ws + o_sf);
    gemm_w<<<dim3(8, 12, 4), 256, 0, stream>>>(w_qkv, ws + o_sf, ws + o_qkv, 768, 0);
    // stok_pad dead; re-zero region for sfa_pad (borders must be 0)
    hipMemsetAsync(ws + o_pad, 0, 663552 * sizeof(float), stream);
    attn_kernel<<<dim3(8, 8, 4), 256, 0, stream>>>(ws + o_qkv, ws + o_sf);
    peadd_kernel<<<8 * 256, 256, 0, stream>>>(ws + o_qkv, w_pe, ws + o_sf);
    gemm_w<<<dim3(8, 4, 4), 256, 0, stream>>>(w_proj, ws + o_sf, ws + o_pad, 256, 1);
    scatter_kernel<<<8 * 16 * 8, 256, 0, stream>>>(ws + o_pad, ws + o_aff, out);
}